// Round 3
// baseline (973.314 us; speedup 1.0000x reference)
//
#include <hip/hip_runtime.h>
#include <stdint.h>

// BatchTopK: x (1024, 65536) f32, keep global top k*1024 = 65536 of relu(x), zero rest.
//
// R8: collapse to 3 dispatches; last-block select+scatter.
// Evidence (R6/R7 profiles): harness re-poison of the 1 GiB workspace runs as
// __amd_rocclr_fillBufferAligned (162us @ 6.6 TB/s each); dur_us in BOTH rounds
// fits ~324us (2 fills) + our-kernel-sum. Our controllable part is ~180us.
// Changes:
//  (a) fuse zero+scan into one kernel (branch-free 8-deep load phase + nt
//      zero-stores interleaved; R6's fused slowness was load serialization,
//      fixed by R7's structure, not by the split itself).
//  (b) select+scatter run in the LAST finishing block (threadfence + done
//      counter), removing 3 launches + inter-kernel cache-drain points.
//  (c) LDS unioned: scan staging (8KB) aliases select's hist+bucket (16KB)
//      -> 16.4KB/block, 8+ blocks/CU.
//  (d) branch-free scatter (cndmask sink pointer) so loads stay pipelined.

#define HDR_CURSOR 0
#define HDR_FLAG   1
#define HDR_THR    2
#define HDR_ICUT   3
#define HDR_DONE   4
#define HIST_OFF   4096       // uint32 ghist[2048] at ws+4096
#define CAND_OFF   16384      // candidate buffer
#define NBINS      2048u
#define BUCKET_CAP 1024u      // expected max bin ~230; flag->fallback if exceeded
#define SCAN_STAGE 1024       // per-block candidate staging (expected ~44/block)
#define ROWS       1024u      // x.shape[0], fixed by the problem
#define SPEC       3.0f       // count(x>=3.0) ~ 90.6k >= K=65536
#define BASE_BITS  0x40400000u  // __float_as_uint(3.0f)

typedef float f32x4 __attribute__((ext_vector_type(4)));

__device__ __forceinline__ uint32_t bin_of(uint32_t key) {
  uint32_t off = key - BASE_BITS;        // key >= BASE_BITS guaranteed by SPEC filter
  uint32_t b = off >> 12;
  return b < NBINS ? b : (NBINS - 1u);
}

__device__ __forceinline__ float max4(float4 a) {
  return fmaxf(fmaxf(a.x, a.y), fmaxf(a.z, a.w));
}

__device__ __forceinline__ uint32_t aload(uint32_t* p) {  // device-scope atomic load
  return atomicAdd(p, 0u);
}

__global__ void k_init(uint32_t* hdr, uint32_t* ghist, uint32_t force_flag) {
  for (uint32_t i = threadIdx.x; i < 64u + NBINS; i += 256u) {
    if (i < 64u) hdr[i] = 0u;
    else ghist[i - 64u] = 0u;
  }
  if (threadIdx.x == 0u) hdr[HDR_FLAG] = force_flag;
}

__device__ __forceinline__ void push4(float4 a, uint32_t gi,
                                      uint32_t* s_cnt, uint2* s_buf) {
  if (a.x >= SPEC) { uint32_t p = atomicAdd(s_cnt, 1u); if (p < SCAN_STAGE) s_buf[p] = make_uint2(__float_as_uint(a.x), gi); }
  if (a.y >= SPEC) { uint32_t p = atomicAdd(s_cnt, 1u); if (p < SCAN_STAGE) s_buf[p] = make_uint2(__float_as_uint(a.y), gi + 1u); }
  if (a.z >= SPEC) { uint32_t p = atomicAdd(s_cnt, 1u); if (p < SCAN_STAGE) s_buf[p] = make_uint2(__float_as_uint(a.z), gi + 2u); }
  if (a.w >= SPEC) { uint32_t p = atomicAdd(s_cnt, 1u); if (p < SCAN_STAGE) s_buf[p] = make_uint2(__float_as_uint(a.w), gi + 3u); }
}

// One kernel: every block zeros its out-slice (nt stores) + scans its x-slice
// (branch-free 8-deep loads), appends candidates + global linear histogram.
// The last block to finish runs selection + sparse scatter.
__global__ __launch_bounds__(256) void k_fused(
    float4* __restrict__ out4, float* __restrict__ out,
    const float4* __restrict__ x4, const float* __restrict__ x,
    uint2* __restrict__ cand, uint32_t* __restrict__ hdr,
    uint32_t* __restrict__ ghist, const int* __restrict__ kptr,
    uint32_t cap, uint32_t n4, uint32_t n) {
  __shared__ uint32_t s_cnt, s_base, s_last, s_sel, s_rank, s_bcnt, s_thr, s_icut;
  __shared__ __align__(16) uint8_t s_mem[16384];
  uint2* s_buf = (uint2*)s_mem;                 // phase 1: [0,8K)
  uint32_t* h = (uint32_t*)s_mem;               // phase 2: [0,8K)   (aliases s_buf)
  uint2* bkt = (uint2*)(s_mem + 8192);          // phase 2: [8K,16K)
  uint32_t tid = threadIdx.x;
  if (tid == 0u) s_cnt = 0u;
  __syncthreads();

  const f32x4 z = {0.f, 0.f, 0.f, 0.f};
  uint32_t stride = gridDim.x * blockDim.x;
  uint32_t i = blockIdx.x * blockDim.x + tid;
  for (; i + 7u * stride < n4; i += 8u * stride) {
    // ---- branch-free phase: 8 independent loads, then the zero stores ----
    float4 a0 = x4[i];
    float4 a1 = x4[i + stride];
    float4 a2 = x4[i + 2u * stride];
    float4 a3 = x4[i + 3u * stride];
    float4 a4 = x4[i + 4u * stride];
    float4 a5 = x4[i + 5u * stride];
    float4 a6 = x4[i + 6u * stride];
    float4 a7 = x4[i + 7u * stride];
    __builtin_nontemporal_store(z, (f32x4*)(out4 + i));
    __builtin_nontemporal_store(z, (f32x4*)(out4 + i + stride));
    __builtin_nontemporal_store(z, (f32x4*)(out4 + i + 2u * stride));
    __builtin_nontemporal_store(z, (f32x4*)(out4 + i + 3u * stride));
    __builtin_nontemporal_store(z, (f32x4*)(out4 + i + 4u * stride));
    __builtin_nontemporal_store(z, (f32x4*)(out4 + i + 5u * stride));
    __builtin_nontemporal_store(z, (f32x4*)(out4 + i + 6u * stride));
    __builtin_nontemporal_store(z, (f32x4*)(out4 + i + 7u * stride));
    float m0 = max4(a0), m1 = max4(a1), m2 = max4(a2), m3 = max4(a3);
    float m4 = max4(a4), m5 = max4(a5), m6 = max4(a6), m7 = max4(a7);
    // ---- rare branchy phase (~70% of ballots skip) ----
    if (__ballot(m0 >= SPEC)) push4(a0, (i) * 4u, &s_cnt, s_buf);
    if (__ballot(m1 >= SPEC)) push4(a1, (i + stride) * 4u, &s_cnt, s_buf);
    if (__ballot(m2 >= SPEC)) push4(a2, (i + 2u * stride) * 4u, &s_cnt, s_buf);
    if (__ballot(m3 >= SPEC)) push4(a3, (i + 3u * stride) * 4u, &s_cnt, s_buf);
    if (__ballot(m4 >= SPEC)) push4(a4, (i + 4u * stride) * 4u, &s_cnt, s_buf);
    if (__ballot(m5 >= SPEC)) push4(a5, (i + 5u * stride) * 4u, &s_cnt, s_buf);
    if (__ballot(m6 >= SPEC)) push4(a6, (i + 6u * stride) * 4u, &s_cnt, s_buf);
    if (__ballot(m7 >= SPEC)) push4(a7, (i + 7u * stride) * 4u, &s_cnt, s_buf);
  }
  for (; i < n4; i += stride) {
    float4 a = x4[i];
    __builtin_nontemporal_store(z, (f32x4*)(out4 + i));
    if (__ballot(max4(a) >= SPEC)) push4(a, i * 4u, &s_cnt, s_buf);
  }
  uint32_t tail0 = n4 * 4u;
  if (blockIdx.x == 0u && tid < (n - tail0)) {
    uint32_t gi = tail0 + tid;
    float v = x[gi];
    out[gi] = 0.f;
    if (v >= SPEC) { uint32_t p = atomicAdd(&s_cnt, 1u); if (p < SCAN_STAGE) s_buf[p] = make_uint2(__float_as_uint(v), gi); }
  }
  __syncthreads();

  // ---- flush block candidates to global ----
  uint32_t cnt = s_cnt;
  if (cnt != 0u) {
    uint32_t wcnt = cnt < (uint32_t)SCAN_STAGE ? cnt : (uint32_t)SCAN_STAGE;
    if (tid == 0u) {
      s_base = atomicAdd(&hdr[HDR_CURSOR], cnt);  // true total
      if (cnt > (uint32_t)SCAN_STAGE) atomicOr(&hdr[HDR_FLAG], 1u);
    }
    __syncthreads();
    uint32_t base = s_base;
    for (uint32_t j = tid; j < wcnt; j += blockDim.x) {
      uint32_t gidx = base + j;
      if (gidx < cap) {
        uint2 c = s_buf[j];
        cand[gidx] = c;
        atomicAdd(&ghist[bin_of(c.x)], 1u);
      }
    }
    if (tid == 0u && base + wcnt > cap) atomicOr(&hdr[HDR_FLAG], 1u);
  }

  // ---- last-block handoff ----
  __threadfence();
  __syncthreads();
  if (tid == 0u) {
    uint32_t d = atomicAdd(&hdr[HDR_DONE], 1u);
    s_last = (d == gridDim.x - 1u) ? 1u : 0u;
  }
  __syncthreads();
  if (s_last == 0u) return;
  __threadfence();

  // ================= SELECT (last block only, 256 threads) =================
  uint32_t K = (uint32_t)kptr[0] * ROWS;
  uint32_t M = aload(&hdr[HDR_CURSOR]);
  uint32_t flag = aload(&hdr[HDR_FLAG]);
  if (flag != 0u || M > cap || M < K) {
    if (tid == 0u) atomicOr(&hdr[HDR_FLAG], 1u);
    return;
  }
  if (K == 0u) return;  // out already zeroed; keep nothing

  for (uint32_t b = tid; b < NBINS; b += 256u) h[b] = ghist[b];
  if (tid == 0u) s_bcnt = 0u;
  __syncthreads();
  // wave 0: suffix scan over 2048 bins to find the bin holding rank K
  if (tid < 64u) {
    uint32_t seg = NBINS >> 6;           // 32 bins per lane
    uint32_t base = tid * seg;
    uint32_t lanesum = 0u;
    for (uint32_t j = 0; j < seg; ++j) lanesum += h[base + j];
    uint32_t s = lanesum;                // inclusive suffix scan across lanes
    for (int d = 1; d < 64; d <<= 1) {
      uint32_t v = (uint32_t)__shfl_down((int)s, d, 64);
      if ((int)tid + d < 64) s += v;
    }
    uint32_t above = s - lanesum;        // total count in lanes > tid
    if (above < K && above + lanesum >= K) {   // exactly one lane matches
      uint32_t r = K - above;
      uint32_t cum = 0u;
      for (int j = (int)seg - 1; j >= 0; --j) {
        uint32_t c = h[base + (uint32_t)j];
        if (cum + c >= r) { s_sel = base + (uint32_t)j; s_rank = r - cum; break; }
        cum += c;
      }
    }
  }
  __syncthreads();
  uint32_t bsel = s_sel;
  uint32_t r = s_rank;                   // 1-indexed rank inside the bin
  uint32_t E = h[bsel];
  if (bsel == NBINS - 1u || E > BUCKET_CAP) {  // clamp bin or oversized bucket
    if (tid == 0u) atomicOr(&hdr[HDR_FLAG], 1u);   // -> exact fallback
    return;
  }
  // collect candidates in bin bsel (4-deep unrolled, 2 keys per uint4)
  const uint4* __restrict__ cand4 = (const uint4*)cand;
  uint32_t M2 = M >> 1;
  uint32_t j = tid;
  for (; j + 768u < M2; j += 1024u) {
    uint4 c0 = cand4[j];
    uint4 c1 = cand4[j + 256u];
    uint4 c2 = cand4[j + 512u];
    uint4 c3 = cand4[j + 768u];
    if (bin_of(c0.x) == bsel) { uint32_t p = atomicAdd(&s_bcnt, 1u); if (p < BUCKET_CAP) bkt[p] = make_uint2(c0.x, c0.y); }
    if (bin_of(c0.z) == bsel) { uint32_t p = atomicAdd(&s_bcnt, 1u); if (p < BUCKET_CAP) bkt[p] = make_uint2(c0.z, c0.w); }
    if (bin_of(c1.x) == bsel) { uint32_t p = atomicAdd(&s_bcnt, 1u); if (p < BUCKET_CAP) bkt[p] = make_uint2(c1.x, c1.y); }
    if (bin_of(c1.z) == bsel) { uint32_t p = atomicAdd(&s_bcnt, 1u); if (p < BUCKET_CAP) bkt[p] = make_uint2(c1.z, c1.w); }
    if (bin_of(c2.x) == bsel) { uint32_t p = atomicAdd(&s_bcnt, 1u); if (p < BUCKET_CAP) bkt[p] = make_uint2(c2.x, c2.y); }
    if (bin_of(c2.z) == bsel) { uint32_t p = atomicAdd(&s_bcnt, 1u); if (p < BUCKET_CAP) bkt[p] = make_uint2(c2.z, c2.w); }
    if (bin_of(c3.x) == bsel) { uint32_t p = atomicAdd(&s_bcnt, 1u); if (p < BUCKET_CAP) bkt[p] = make_uint2(c3.x, c3.y); }
    if (bin_of(c3.z) == bsel) { uint32_t p = atomicAdd(&s_bcnt, 1u); if (p < BUCKET_CAP) bkt[p] = make_uint2(c3.z, c3.w); }
  }
  for (; j < M2; j += 256u) {
    uint4 c = cand4[j];
    if (bin_of(c.x) == bsel) { uint32_t p = atomicAdd(&s_bcnt, 1u); if (p < BUCKET_CAP) bkt[p] = make_uint2(c.x, c.y); }
    if (bin_of(c.z) == bsel) { uint32_t p = atomicAdd(&s_bcnt, 1u); if (p < BUCKET_CAP) bkt[p] = make_uint2(c.z, c.w); }
  }
  if (tid == 0u && (M & 1u)) {
    uint2 c = cand[M - 1u];
    if (bin_of(c.x) == bsel) { uint32_t p = atomicAdd(&s_bcnt, 1u); if (p < BUCKET_CAP) bkt[p] = c; }
  }
  __syncthreads();
  // exact selection: entry with composite rank r-1 (key desc, idx asc)
  for (uint32_t e = tid; e < E; e += 256u) {
    uint2 me = bkt[e];
    uint32_t rank = 0u;
    for (uint32_t jj = 0; jj < E; ++jj) {
      uint2 o = bkt[jj];
      rank += (o.x > me.x || (o.x == me.x && o.y < me.y)) ? 1u : 0u;
    }
    if (rank == r - 1u) { s_thr = me.x; s_icut = me.y; hdr[HDR_THR] = me.x; hdr[HDR_ICUT] = me.y; }
  }
  __syncthreads();

  // ================= SCATTER (branch-free: sink pointer) =================
  uint32_t thr = s_thr, icut = s_icut;
  float* sink = (float*)&hdr[48];        // dummy target for dropped lanes
#pragma unroll 8
  for (uint32_t q = tid; q < M; q += 256u) {
    uint2 c = cand[q];
    bool keep = (c.x > thr) || (c.x == thr && c.y <= icut);
    float* p = keep ? &out[c.y] : sink;
    *p = __uint_as_float(c.x);
  }
}

// Exact general fallback (gated; never taken for the fixed bench input).
// Single block, full radix select over all data + dense rewrite. Slow but correct.
__global__ __launch_bounds__(1024) void k_fallback(
    const float* __restrict__ x, float* __restrict__ out,
    const int* __restrict__ kptr, const uint32_t* __restrict__ hdr, uint32_t n) {
  if (hdr[HDR_FLAG] == 0u) return;
  __shared__ uint32_t hist[2048];
  __shared__ uint32_t s_sel, s_rank, s_found, s_eqcnt, s_icut;
  __shared__ uint32_t eq_idx[4096];
  uint32_t tid = threadIdx.x;
  uint32_t K = (uint32_t)kptr[0] * ROWS;
  uint32_t prefix = 0u;
  uint32_t R = K;
  bool zero_thr = (K == 0u);
  for (int lvl = 0; lvl < 3 && !zero_thr; ++lvl) {
    uint32_t shift = (lvl == 0) ? 21u : (lvl == 1 ? 10u : 0u);
    uint32_t nb = (lvl == 2) ? 1024u : 2048u;
    for (uint32_t b = tid; b < nb; b += 1024u) hist[b] = 0u;
    __syncthreads();
    for (uint32_t i = tid; i < n; i += 1024u) {
      float v = x[i];
      uint32_t key = (v > 0.f) ? __float_as_uint(v) : 0u;
      bool valid = (key != 0u);
      if (lvl == 1) valid = valid && ((key >> 21) == prefix);
      if (lvl == 2) valid = valid && ((key >> 10) == prefix);
      if (valid) atomicAdd(&hist[(key >> shift) & (nb - 1u)], 1u);
    }
    __syncthreads();
    if (tid == 0u) {
      uint32_t cum = 0u, sel = 0u, rr = R, found = 0u;
      for (int b = (int)nb - 1; b >= 0; --b) {
        uint32_t c = hist[b];
        if (cum + c >= R) { sel = (uint32_t)b; rr = R - cum; found = 1u; break; }
        cum += c;
      }
      s_sel = sel; s_rank = rr; s_found = found;
    }
    __syncthreads();
    if (s_found == 0u) {
      zero_thr = true;  // fewer than K positives: keep all positives
    } else {
      uint32_t sel = s_sel;
      R = s_rank;
      if (lvl == 0) prefix = sel;
      else if (lvl == 1) prefix = (prefix << 11) | sel;
      else prefix = (prefix << 10) | sel;
    }
    __syncthreads();
  }
  uint32_t thr_key = zero_thr ? 0u : prefix;
  uint32_t icut = 0xFFFFFFFFu;
  if (!zero_thr) {
    uint32_t E = hist[thr_key & 1023u];
    uint32_t T = R;
    if (T < E) {
      if (tid == 0u) { s_eqcnt = 0u; s_icut = 0xFFFFFFFFu; }
      __syncthreads();
      for (uint32_t i = tid; i < n; i += 1024u) {
        float v = x[i];
        if (v > 0.f && __float_as_uint(v) == thr_key) {
          uint32_t p = atomicAdd(&s_eqcnt, 1u);
          if (p < 4096u) eq_idx[p] = i;
        }
      }
      __syncthreads();
      uint32_t ec = s_eqcnt < 4096u ? s_eqcnt : 4096u;
      for (uint32_t e = tid; e < ec; e += 1024u) {
        uint32_t me = eq_idx[e];
        uint32_t rank = 0u;
        for (uint32_t j = 0; j < ec; ++j) rank += (eq_idx[j] < me) ? 1u : 0u;
        if (rank == T - 1u) s_icut = me;
      }
      __syncthreads();
      icut = s_icut;
    }
  }
  for (uint32_t i = tid; i < n; i += 1024u) {
    float v = x[i];
    uint32_t key = (v > 0.f) ? __float_as_uint(v) : 0u;
    bool keep = (key > thr_key) || (key != 0u && key == thr_key && i <= icut);
    out[i] = keep ? v : 0.f;
  }
}

extern "C" void kernel_launch(void* const* d_in, const int* in_sizes, int n_in,
                              void* d_out, int out_size, void* d_ws, size_t ws_size,
                              hipStream_t stream) {
  const float* x = (const float*)d_in[0];
  const int* kptr = (const int*)d_in[1];
  float* out = (float*)d_out;
  uint32_t n = (uint32_t)in_sizes[0];
  uint32_t n4 = n >> 2;

  uint32_t* hdr = (uint32_t*)d_ws;
  uint32_t* ghist = (uint32_t*)((char*)d_ws + HIST_OFF);
  uint2* cand = (uint2*)((char*)d_ws + CAND_OFF);
  uint32_t cap = (ws_size > (size_t)CAND_OFF) ? (uint32_t)((ws_size - CAND_OFF) / 8) : 0u;
  // If ws can't hold candidates with margin, force the exact fallback path.
  uint32_t force = (cap < 131072u) ? 1u : 0u;

  k_init<<<1, 256, 0, stream>>>(hdr, ghist, force);
  k_fused<<<2048, 256, 0, stream>>>((float4*)out, out, (const float4*)x, x,
                                    cand, hdr, ghist, kptr, cap, n4, n);
  k_fallback<<<1, 1024, 0, stream>>>(x, out, kptr, hdr, n);
}

// Round 4
// 502.429 us; speedup vs baseline: 1.9372x; 1.9372x over previous
//
#include <hip/hip_runtime.h>
#include <stdint.h>

// BatchTopK: x (1024, 65536) f32, keep global top k*1024 = 65536 of relu(x), zero rest.
//
// R9: remove nontemporal stores from the pipeline.
// Cross-round evidence: plain-store fillBuffer = 6.6 TB/s @ 10% occupancy;
// every nt-store variant (R6 fused 1.95 TB/s, R7 nt-zero ~2 TB/s inferred,
// R8 per-wave-interleaved 0.59 TB/s) is 3x+ slower. nt bypasses L2 write
// combining -> ~2 TB/s cap. R8's last-block handoff is also reverted (one
// variable at a time; R7 structure is the known-good base).
// Changes vs R7:
//  (a) k_zero deleted; out[] zeroed via hipMemsetAsync (rocclr fill path,
//      6.6 TB/s measured, graph-capture-legal memset node).
//  (b) everything else byte-identical to R7's known-good kernels.

#define HDR_CURSOR 0
#define HDR_FLAG   1
#define HDR_THR    2
#define HDR_ICUT   3
#define HIST_OFF   4096       // uint32 hist[2048] at ws+4096
#define CAND_OFF   16384      // candidate buffer
#define NBINS      2048u
#define BUCKET_CAP 6144u
#define SCAN_STAGE 1024       // per-block candidate staging (expected ~44/block)
#define ROWS       1024u      // x.shape[0], fixed by the problem
#define SPEC       3.0f       // count(x>=3.0) ~ 90.6k >= K=65536
#define BASE_BITS  0x40400000u  // __float_as_uint(3.0f)

__device__ __forceinline__ uint32_t bin_of(uint32_t key) {
  uint32_t off = key - BASE_BITS;        // key >= BASE_BITS guaranteed by SPEC filter
  uint32_t b = off >> 12;
  return b < NBINS ? b : (NBINS - 1u);
}

__device__ __forceinline__ float max4(float4 a) {
  return fmaxf(fmaxf(a.x, a.y), fmaxf(a.z, a.w));
}

__global__ void k_init(uint32_t* hdr, uint32_t* ghist, uint32_t force_flag) {
  for (uint32_t i = threadIdx.x; i < 64u + NBINS; i += 256u) {
    if (i < 64u) hdr[i] = 0u;
    else ghist[i - 64u] = 0u;
  }
  if (threadIdx.x == 0u) hdr[HDR_FLAG] = force_flag;
}

__device__ __forceinline__ void push4(float4 a, uint32_t gi,
                                      uint32_t* s_cnt, uint2* s_buf) {
  if (a.x >= SPEC) { uint32_t p = atomicAdd(s_cnt, 1u); if (p < SCAN_STAGE) s_buf[p] = make_uint2(__float_as_uint(a.x), gi); }
  if (a.y >= SPEC) { uint32_t p = atomicAdd(s_cnt, 1u); if (p < SCAN_STAGE) s_buf[p] = make_uint2(__float_as_uint(a.y), gi + 1u); }
  if (a.z >= SPEC) { uint32_t p = atomicAdd(s_cnt, 1u); if (p < SCAN_STAGE) s_buf[p] = make_uint2(__float_as_uint(a.z), gi + 2u); }
  if (a.w >= SPEC) { uint32_t p = atomicAdd(s_cnt, 1u); if (p < SCAN_STAGE) s_buf[p] = make_uint2(__float_as_uint(a.w), gi + 3u); }
}

// Read-only scan: branch-free 8-deep load phase, then rare branchy pushes.
// 2048 blocks x 256 thr: 32 float4/thread = 4 outer iterations exactly.
__global__ __launch_bounds__(256) void k_scan(
    const float4* __restrict__ x4, const float* __restrict__ x,
    uint2* __restrict__ cand, uint32_t* __restrict__ hdr,
    uint32_t* __restrict__ ghist,
    uint32_t cap, uint32_t n4, uint32_t n) {
  __shared__ uint32_t s_cnt;
  __shared__ uint32_t s_base;
  __shared__ uint2 s_buf[SCAN_STAGE];
  if (threadIdx.x == 0u) s_cnt = 0u;
  __syncthreads();

  uint32_t stride = gridDim.x * blockDim.x;
  uint32_t i = blockIdx.x * blockDim.x + threadIdx.x;
  for (; i + 7u * stride < n4; i += 8u * stride) {
    // ---- branch-free phase: 8 independent loads, nothing between them ----
    float4 a0 = x4[i];
    float4 a1 = x4[i + stride];
    float4 a2 = x4[i + 2u * stride];
    float4 a3 = x4[i + 3u * stride];
    float4 a4 = x4[i + 4u * stride];
    float4 a5 = x4[i + 5u * stride];
    float4 a6 = x4[i + 6u * stride];
    float4 a7 = x4[i + 7u * stride];
    float m0 = max4(a0), m1 = max4(a1), m2 = max4(a2), m3 = max4(a3);
    float m4 = max4(a4), m5 = max4(a5), m6 = max4(a6), m7 = max4(a7);
    // ---- rare branchy phase: per-vector wave-uniform skip (~70% skip) ----
    if (__ballot(m0 >= SPEC)) push4(a0, (i) * 4u, &s_cnt, s_buf);
    if (__ballot(m1 >= SPEC)) push4(a1, (i + stride) * 4u, &s_cnt, s_buf);
    if (__ballot(m2 >= SPEC)) push4(a2, (i + 2u * stride) * 4u, &s_cnt, s_buf);
    if (__ballot(m3 >= SPEC)) push4(a3, (i + 3u * stride) * 4u, &s_cnt, s_buf);
    if (__ballot(m4 >= SPEC)) push4(a4, (i + 4u * stride) * 4u, &s_cnt, s_buf);
    if (__ballot(m5 >= SPEC)) push4(a5, (i + 5u * stride) * 4u, &s_cnt, s_buf);
    if (__ballot(m6 >= SPEC)) push4(a6, (i + 6u * stride) * 4u, &s_cnt, s_buf);
    if (__ballot(m7 >= SPEC)) push4(a7, (i + 7u * stride) * 4u, &s_cnt, s_buf);
  }
  for (; i < n4; i += stride) {
    float4 a = x4[i];
    if (__ballot(max4(a) >= SPEC)) push4(a, i * 4u, &s_cnt, s_buf);
  }
  uint32_t tail0 = n4 * 4u;
  if (blockIdx.x == 0u && threadIdx.x < (n - tail0)) {
    uint32_t gi = tail0 + threadIdx.x;
    float v = x[gi];
    if (v >= SPEC) { uint32_t p = atomicAdd(&s_cnt, 1u); if (p < SCAN_STAGE) s_buf[p] = make_uint2(__float_as_uint(v), gi); }
  }
  __syncthreads();
  uint32_t cnt = s_cnt;
  if (cnt == 0u) return;
  uint32_t wcnt = cnt < (uint32_t)SCAN_STAGE ? cnt : (uint32_t)SCAN_STAGE;
  if (threadIdx.x == 0u) {
    s_base = atomicAdd(&hdr[HDR_CURSOR], cnt);  // true total (drops flagged)
    if (cnt > (uint32_t)SCAN_STAGE) atomicOr(&hdr[HDR_FLAG], 1u);
  }
  __syncthreads();
  uint32_t base = s_base;
  for (uint32_t j = threadIdx.x; j < wcnt; j += blockDim.x) {
    uint32_t gidx = base + j;
    if (gidx < cap) {
      uint2 c = s_buf[j];
      cand[gidx] = c;
      atomicAdd(&ghist[bin_of(c.x)], 1u);   // ~44/block, spread over 2048 words
    }
  }
  if (threadIdx.x == 0u && base + wcnt > cap) atomicOr(&hdr[HDR_FLAG], 1u);
}

// Single block: pick rank-K bin from the prebuilt 2048-bin linear histogram,
// collect that bin's candidates (expected ~220), exact composite-rank select.
__global__ __launch_bounds__(1024) void k_select(
    const uint2* __restrict__ cand, uint32_t* __restrict__ hdr,
    const uint32_t* __restrict__ ghist,
    const int* __restrict__ kptr, uint32_t cap) {
  __shared__ uint32_t h[NBINS];
  __shared__ uint32_t s_sel, s_rank, s_bcnt;
  __shared__ uint2 bkt[BUCKET_CAP];
  uint32_t tid = threadIdx.x;
  uint32_t K = (uint32_t)kptr[0] * ROWS;
  uint32_t M = hdr[HDR_CURSOR];
  if (hdr[HDR_FLAG] != 0u || M > cap || M < K) {
    if (tid == 0u) hdr[HDR_FLAG] = 1u;
    return;
  }
  if (K == 0u) {  // keep nothing; candidate keys are finite positive floats < 0xFFFFFFFF
    if (tid == 0u) { hdr[HDR_THR] = 0xFFFFFFFFu; hdr[HDR_ICUT] = 0xFFFFFFFFu; }
    return;
  }
  h[tid] = ghist[tid];
  h[tid + 1024u] = ghist[tid + 1024u];
  if (tid == 0u) s_bcnt = 0u;
  __syncthreads();
  // wave 0: suffix scan over 2048 bins to find the bin holding rank K
  if (tid < 64u) {
    uint32_t seg = NBINS >> 6;           // 32 bins per lane
    uint32_t base = tid * seg;
    uint32_t lanesum = 0u;
    for (uint32_t j = 0; j < seg; ++j) lanesum += h[base + j];
    uint32_t s = lanesum;                // inclusive suffix scan across lanes
    for (int d = 1; d < 64; d <<= 1) {
      uint32_t v = (uint32_t)__shfl_down((int)s, d, 64);
      if ((int)tid + d < 64) s += v;
    }
    uint32_t above = s - lanesum;        // total count in lanes > tid
    if (above < K && above + lanesum >= K) {   // exactly one lane matches
      uint32_t r = K - above;
      uint32_t cum = 0u;
      for (int j = (int)seg - 1; j >= 0; --j) {
        uint32_t c = h[base + (uint32_t)j];
        if (cum + c >= r) { s_sel = base + (uint32_t)j; s_rank = r - cum; break; }
        cum += c;
      }
    }
  }
  __syncthreads();
  uint32_t bsel = s_sel;
  uint32_t r = s_rank;                   // 1-indexed rank inside the bin
  uint32_t E = h[bsel];
  if (bsel == NBINS - 1u || E > BUCKET_CAP) {  // clamp bin or oversized bucket
    if (tid == 0u) hdr[HDR_FLAG] = 1u;         // -> exact fallback
    return;
  }
  // single pass: collect candidates in bin bsel (x4 unrolled, 8 keys/iter)
  const uint4* __restrict__ cand4 = (const uint4*)cand;
  uint32_t M2 = M >> 1;
  uint32_t j = tid;
  for (; j + 3072u < M2; j += 4096u) {
    uint4 c0 = cand4[j];
    uint4 c1 = cand4[j + 1024u];
    uint4 c2 = cand4[j + 2048u];
    uint4 c3 = cand4[j + 3072u];
    if (bin_of(c0.x) == bsel) { uint32_t p = atomicAdd(&s_bcnt, 1u); if (p < BUCKET_CAP) bkt[p] = make_uint2(c0.x, c0.y); }
    if (bin_of(c0.z) == bsel) { uint32_t p = atomicAdd(&s_bcnt, 1u); if (p < BUCKET_CAP) bkt[p] = make_uint2(c0.z, c0.w); }
    if (bin_of(c1.x) == bsel) { uint32_t p = atomicAdd(&s_bcnt, 1u); if (p < BUCKET_CAP) bkt[p] = make_uint2(c1.x, c1.y); }
    if (bin_of(c1.z) == bsel) { uint32_t p = atomicAdd(&s_bcnt, 1u); if (p < BUCKET_CAP) bkt[p] = make_uint2(c1.z, c1.w); }
    if (bin_of(c2.x) == bsel) { uint32_t p = atomicAdd(&s_bcnt, 1u); if (p < BUCKET_CAP) bkt[p] = make_uint2(c2.x, c2.y); }
    if (bin_of(c2.z) == bsel) { uint32_t p = atomicAdd(&s_bcnt, 1u); if (p < BUCKET_CAP) bkt[p] = make_uint2(c2.z, c2.w); }
    if (bin_of(c3.x) == bsel) { uint32_t p = atomicAdd(&s_bcnt, 1u); if (p < BUCKET_CAP) bkt[p] = make_uint2(c3.x, c3.y); }
    if (bin_of(c3.z) == bsel) { uint32_t p = atomicAdd(&s_bcnt, 1u); if (p < BUCKET_CAP) bkt[p] = make_uint2(c3.z, c3.w); }
  }
  for (; j < M2; j += 1024u) {
    uint4 c = cand4[j];
    if (bin_of(c.x) == bsel) { uint32_t p = atomicAdd(&s_bcnt, 1u); if (p < BUCKET_CAP) bkt[p] = make_uint2(c.x, c.y); }
    if (bin_of(c.z) == bsel) { uint32_t p = atomicAdd(&s_bcnt, 1u); if (p < BUCKET_CAP) bkt[p] = make_uint2(c.z, c.w); }
  }
  if (tid == 0u && (M & 1u)) {
    uint2 c = cand[M - 1u];
    if (bin_of(c.x) == bsel) { uint32_t p = atomicAdd(&s_bcnt, 1u); if (p < BUCKET_CAP) bkt[p] = c; }
  }
  __syncthreads();
  // exact selection: entry with composite rank r-1 (key desc, idx asc)
  for (uint32_t e = tid; e < E; e += 1024u) {
    uint2 me = bkt[e];
    uint32_t rank = 0u;
    for (uint32_t jj = 0; jj < E; ++jj) {
      uint2 o = bkt[jj];
      rank += (o.x > me.x || (o.x == me.x && o.y < me.y)) ? 1u : 0u;
    }
    if (rank == r - 1u) { hdr[HDR_THR] = me.x; hdr[HDR_ICUT] = me.y; }
  }
}

// Sparse scatter of kept candidates into the zeroed output.
__global__ __launch_bounds__(256) void k_scatter(
    const uint2* __restrict__ cand, const uint32_t* __restrict__ hdr,
    float* __restrict__ out, uint32_t cap) {
  if (hdr[HDR_FLAG] != 0u) return;
  uint32_t M = hdr[HDR_CURSOR]; if (M > cap) M = cap;
  uint32_t thr = hdr[HDR_THR], icut = hdr[HDR_ICUT];
  uint32_t stride = gridDim.x * blockDim.x;
  for (uint32_t i = blockIdx.x * blockDim.x + threadIdx.x; i < M; i += stride) {
    uint2 c = cand[i];
    if (c.x > thr || (c.x == thr && c.y <= icut)) out[c.y] = __uint_as_float(c.x);
  }
}

// Exact general fallback (gated; never taken for the fixed bench input).
// Single block, full radix select over all data + dense rewrite. Slow but correct.
__global__ __launch_bounds__(1024) void k_fallback(
    const float* __restrict__ x, float* __restrict__ out,
    const int* __restrict__ kptr, const uint32_t* __restrict__ hdr, uint32_t n) {
  if (hdr[HDR_FLAG] == 0u) return;
  __shared__ uint32_t hist[2048];
  __shared__ uint32_t s_sel, s_rank, s_found, s_eqcnt, s_icut;
  __shared__ uint32_t eq_idx[4096];
  uint32_t tid = threadIdx.x;
  uint32_t K = (uint32_t)kptr[0] * ROWS;
  uint32_t prefix = 0u;
  uint32_t R = K;
  bool zero_thr = (K == 0u);
  for (int lvl = 0; lvl < 3 && !zero_thr; ++lvl) {
    uint32_t shift = (lvl == 0) ? 21u : (lvl == 1 ? 10u : 0u);
    uint32_t nb = (lvl == 2) ? 1024u : 2048u;
    for (uint32_t b = tid; b < nb; b += 1024u) hist[b] = 0u;
    __syncthreads();
    for (uint32_t i = tid; i < n; i += 1024u) {
      float v = x[i];
      uint32_t key = (v > 0.f) ? __float_as_uint(v) : 0u;
      bool valid = (key != 0u);
      if (lvl == 1) valid = valid && ((key >> 21) == prefix);
      if (lvl == 2) valid = valid && ((key >> 10) == prefix);
      if (valid) atomicAdd(&hist[(key >> shift) & (nb - 1u)], 1u);
    }
    __syncthreads();
    if (tid == 0u) {
      uint32_t cum = 0u, sel = 0u, rr = R, found = 0u;
      for (int b = (int)nb - 1; b >= 0; --b) {
        uint32_t c = hist[b];
        if (cum + c >= R) { sel = (uint32_t)b; rr = R - cum; found = 1u; break; }
        cum += c;
      }
      s_sel = sel; s_rank = rr; s_found = found;
    }
    __syncthreads();
    if (s_found == 0u) {
      zero_thr = true;  // fewer than K positives: keep all positives
    } else {
      uint32_t sel = s_sel;
      R = s_rank;
      if (lvl == 0) prefix = sel;
      else if (lvl == 1) prefix = (prefix << 11) | sel;
      else prefix = (prefix << 10) | sel;
    }
    __syncthreads();
  }
  uint32_t thr_key = zero_thr ? 0u : prefix;
  uint32_t icut = 0xFFFFFFFFu;
  if (!zero_thr) {
    uint32_t E = hist[thr_key & 1023u];
    uint32_t T = R;
    if (T < E) {
      if (tid == 0u) { s_eqcnt = 0u; s_icut = 0xFFFFFFFFu; }
      __syncthreads();
      for (uint32_t i = tid; i < n; i += 1024u) {
        float v = x[i];
        if (v > 0.f && __float_as_uint(v) == thr_key) {
          uint32_t p = atomicAdd(&s_eqcnt, 1u);
          if (p < 4096u) eq_idx[p] = i;
        }
      }
      __syncthreads();
      uint32_t ec = s_eqcnt < 4096u ? s_eqcnt : 4096u;
      for (uint32_t e = tid; e < ec; e += 1024u) {
        uint32_t me = eq_idx[e];
        uint32_t rank = 0u;
        for (uint32_t j = 0; j < ec; ++j) rank += (eq_idx[j] < me) ? 1u : 0u;
        if (rank == T - 1u) s_icut = me;
      }
      __syncthreads();
      icut = s_icut;
    }
  }
  for (uint32_t i = tid; i < n; i += 1024u) {
    float v = x[i];
    uint32_t key = (v > 0.f) ? __float_as_uint(v) : 0u;
    bool keep = (key > thr_key) || (key != 0u && key == thr_key && i <= icut);
    out[i] = keep ? v : 0.f;
  }
}

extern "C" void kernel_launch(void* const* d_in, const int* in_sizes, int n_in,
                              void* d_out, int out_size, void* d_ws, size_t ws_size,
                              hipStream_t stream) {
  const float* x = (const float*)d_in[0];
  const int* kptr = (const int*)d_in[1];
  float* out = (float*)d_out;
  uint32_t n = (uint32_t)in_sizes[0];
  uint32_t n4 = n >> 2;

  uint32_t* hdr = (uint32_t*)d_ws;
  uint32_t* ghist = (uint32_t*)((char*)d_ws + HIST_OFF);
  uint2* cand = (uint2*)((char*)d_ws + CAND_OFF);
  uint32_t cap = (ws_size > (size_t)CAND_OFF) ? (uint32_t)((ws_size - CAND_OFF) / 8) : 0u;
  // If ws can't hold candidates with margin, force the exact fallback path.
  uint32_t force = (cap < 131072u) ? 1u : 0u;

  k_init<<<1, 256, 0, stream>>>(hdr, ghist, force);
  k_scan<<<2048, 256, 0, stream>>>((const float4*)x, x, cand, hdr, ghist, cap, n4, n);
  // Zero the output via the rocclr fill path (plain stores, 6.6 TB/s measured;
  // our nt-store kernels capped at ~2 TB/s). Graph-capture-legal memset node.
  hipMemsetAsync(out, 0, (size_t)n * 4u, stream);
  k_select<<<1, 1024, 0, stream>>>(cand, hdr, ghist, kptr, cap);
  k_fallback<<<1, 1024, 0, stream>>>(x, out, kptr, hdr, n);
  k_scatter<<<512, 256, 0, stream>>>(cand, hdr, out, cap);
}

// Round 5
// 501.969 us; speedup vs baseline: 1.9390x; 1.0009x over previous
//
#include <hip/hip_runtime.h>
#include <stdint.h>

// BatchTopK: x (1024, 65536) f32, keep global top k*1024 = 65536 of relu(x), zero rest.
//
// R10: restore DRAM page locality in the scan.
// Fit across R6-R9: dur = ~330us fixed floor (two 1-GiB ws-poison fills @6.5TB/s,
// outside our control) + ours. Ours ~172us, of which scan ~105us (2.4 TB/s).
// Theory: the 8-deep unroll reads 8 streams 8MB apart per wave -> ~16k
// concurrent streams chip-wide -> HBM page-open thrash. The 6.29 TB/s m13
// copy ubench and the 6.6 TB/s fill both sweep ONE contiguous window.
// Change (single variable vs R9): scan loop = contiguous grid-stride sweep,
// one ballot per adjacent float4 PAIR (wave reads 2KB contiguous, 2 loads in
// flight, ~50% ballots skip). Everything else identical to R9.

#define HDR_CURSOR 0
#define HDR_FLAG   1
#define HDR_THR    2
#define HDR_ICUT   3
#define HIST_OFF   4096       // uint32 hist[2048] at ws+4096
#define CAND_OFF   16384      // candidate buffer
#define NBINS      2048u
#define BUCKET_CAP 6144u
#define SCAN_STAGE 1024       // per-block candidate staging (expected ~44/block)
#define ROWS       1024u      // x.shape[0], fixed by the problem
#define SPEC       3.0f       // count(x>=3.0) ~ 90.6k >= K=65536
#define BASE_BITS  0x40400000u  // __float_as_uint(3.0f)

__device__ __forceinline__ uint32_t bin_of(uint32_t key) {
  uint32_t off = key - BASE_BITS;        // key >= BASE_BITS guaranteed by SPEC filter
  uint32_t b = off >> 12;
  return b < NBINS ? b : (NBINS - 1u);
}

__device__ __forceinline__ float max4(float4 a) {
  return fmaxf(fmaxf(a.x, a.y), fmaxf(a.z, a.w));
}

__global__ void k_init(uint32_t* hdr, uint32_t* ghist, uint32_t force_flag) {
  for (uint32_t i = threadIdx.x; i < 64u + NBINS; i += 256u) {
    if (i < 64u) hdr[i] = 0u;
    else ghist[i - 64u] = 0u;
  }
  if (threadIdx.x == 0u) hdr[HDR_FLAG] = force_flag;
}

__device__ __forceinline__ void push4(float4 a, uint32_t gi,
                                      uint32_t* s_cnt, uint2* s_buf) {
  if (a.x >= SPEC) { uint32_t p = atomicAdd(s_cnt, 1u); if (p < SCAN_STAGE) s_buf[p] = make_uint2(__float_as_uint(a.x), gi); }
  if (a.y >= SPEC) { uint32_t p = atomicAdd(s_cnt, 1u); if (p < SCAN_STAGE) s_buf[p] = make_uint2(__float_as_uint(a.y), gi + 1u); }
  if (a.z >= SPEC) { uint32_t p = atomicAdd(s_cnt, 1u); if (p < SCAN_STAGE) s_buf[p] = make_uint2(__float_as_uint(a.z), gi + 2u); }
  if (a.w >= SPEC) { uint32_t p = atomicAdd(s_cnt, 1u); if (p < SCAN_STAGE) s_buf[p] = make_uint2(__float_as_uint(a.w), gi + 3u); }
}

// Read-only scan: contiguous grid-stride sweep (m13 copy-ubench pattern).
// Each thread handles an ADJACENT pair of float4s -> the whole chip reads one
// contiguous ~16MB window at a time, sweeping x in 16 steps (DRAM page-local).
__global__ __launch_bounds__(256) void k_scan(
    const float4* __restrict__ x4, const float* __restrict__ x,
    uint2* __restrict__ cand, uint32_t* __restrict__ hdr,
    uint32_t* __restrict__ ghist,
    uint32_t cap, uint32_t n4, uint32_t n) {
  __shared__ uint32_t s_cnt;
  __shared__ uint32_t s_base;
  __shared__ uint2 s_buf[SCAN_STAGE];
  if (threadIdx.x == 0u) s_cnt = 0u;
  __syncthreads();

  uint32_t nthreads = gridDim.x * blockDim.x;
  uint32_t npair = n4 >> 1;
  for (uint32_t g = blockIdx.x * blockDim.x + threadIdx.x; g < npair; g += nthreads) {
    float4 a = x4[2u * g];
    float4 b = x4[2u * g + 1u];
    float m = fmaxf(max4(a), max4(b));
    if (__ballot(m >= SPEC)) {           // ~50% of pair-ballots skip
      push4(a, 8u * g, &s_cnt, s_buf);
      push4(b, 8u * g + 4u, &s_cnt, s_buf);
    }
  }
  // tails (n4 odd and/or n not multiple of 4) -- no-ops for the bench shape
  if (blockIdx.x == 0u && (n4 & 1u) && threadIdx.x == 0u) {
    float4 a = x4[n4 - 1u];
    if (max4(a) >= SPEC) push4(a, (n4 - 1u) * 4u, &s_cnt, s_buf);
  }
  uint32_t tail0 = n4 * 4u;
  if (blockIdx.x == 0u && threadIdx.x < (n - tail0)) {
    uint32_t gi = tail0 + threadIdx.x;
    float v = x[gi];
    if (v >= SPEC) { uint32_t p = atomicAdd(&s_cnt, 1u); if (p < SCAN_STAGE) s_buf[p] = make_uint2(__float_as_uint(v), gi); }
  }
  __syncthreads();
  uint32_t cnt = s_cnt;
  if (cnt == 0u) return;
  uint32_t wcnt = cnt < (uint32_t)SCAN_STAGE ? cnt : (uint32_t)SCAN_STAGE;
  if (threadIdx.x == 0u) {
    s_base = atomicAdd(&hdr[HDR_CURSOR], cnt);  // true total (drops flagged)
    if (cnt > (uint32_t)SCAN_STAGE) atomicOr(&hdr[HDR_FLAG], 1u);
  }
  __syncthreads();
  uint32_t base = s_base;
  for (uint32_t j = threadIdx.x; j < wcnt; j += blockDim.x) {
    uint32_t gidx = base + j;
    if (gidx < cap) {
      uint2 c = s_buf[j];
      cand[gidx] = c;
      atomicAdd(&ghist[bin_of(c.x)], 1u);   // ~44/block, spread over 2048 words
    }
  }
  if (threadIdx.x == 0u && base + wcnt > cap) atomicOr(&hdr[HDR_FLAG], 1u);
}

// Single block: pick rank-K bin from the prebuilt 2048-bin linear histogram,
// collect that bin's candidates (expected ~220), exact composite-rank select.
__global__ __launch_bounds__(1024) void k_select(
    const uint2* __restrict__ cand, uint32_t* __restrict__ hdr,
    const uint32_t* __restrict__ ghist,
    const int* __restrict__ kptr, uint32_t cap) {
  __shared__ uint32_t h[NBINS];
  __shared__ uint32_t s_sel, s_rank, s_bcnt;
  __shared__ uint2 bkt[BUCKET_CAP];
  uint32_t tid = threadIdx.x;
  uint32_t K = (uint32_t)kptr[0] * ROWS;
  uint32_t M = hdr[HDR_CURSOR];
  if (hdr[HDR_FLAG] != 0u || M > cap || M < K) {
    if (tid == 0u) hdr[HDR_FLAG] = 1u;
    return;
  }
  if (K == 0u) {  // keep nothing; candidate keys are finite positive floats < 0xFFFFFFFF
    if (tid == 0u) { hdr[HDR_THR] = 0xFFFFFFFFu; hdr[HDR_ICUT] = 0xFFFFFFFFu; }
    return;
  }
  h[tid] = ghist[tid];
  h[tid + 1024u] = ghist[tid + 1024u];
  if (tid == 0u) s_bcnt = 0u;
  __syncthreads();
  // wave 0: suffix scan over 2048 bins to find the bin holding rank K
  if (tid < 64u) {
    uint32_t seg = NBINS >> 6;           // 32 bins per lane
    uint32_t base = tid * seg;
    uint32_t lanesum = 0u;
    for (uint32_t j = 0; j < seg; ++j) lanesum += h[base + j];
    uint32_t s = lanesum;                // inclusive suffix scan across lanes
    for (int d = 1; d < 64; d <<= 1) {
      uint32_t v = (uint32_t)__shfl_down((int)s, d, 64);
      if ((int)tid + d < 64) s += v;
    }
    uint32_t above = s - lanesum;        // total count in lanes > tid
    if (above < K && above + lanesum >= K) {   // exactly one lane matches
      uint32_t r = K - above;
      uint32_t cum = 0u;
      for (int j = (int)seg - 1; j >= 0; --j) {
        uint32_t c = h[base + (uint32_t)j];
        if (cum + c >= r) { s_sel = base + (uint32_t)j; s_rank = r - cum; break; }
        cum += c;
      }
    }
  }
  __syncthreads();
  uint32_t bsel = s_sel;
  uint32_t r = s_rank;                   // 1-indexed rank inside the bin
  uint32_t E = h[bsel];
  if (bsel == NBINS - 1u || E > BUCKET_CAP) {  // clamp bin or oversized bucket
    if (tid == 0u) hdr[HDR_FLAG] = 1u;         // -> exact fallback
    return;
  }
  // single pass: collect candidates in bin bsel (x4 unrolled, 8 keys/iter)
  const uint4* __restrict__ cand4 = (const uint4*)cand;
  uint32_t M2 = M >> 1;
  uint32_t j = tid;
  for (; j + 3072u < M2; j += 4096u) {
    uint4 c0 = cand4[j];
    uint4 c1 = cand4[j + 1024u];
    uint4 c2 = cand4[j + 2048u];
    uint4 c3 = cand4[j + 3072u];
    if (bin_of(c0.x) == bsel) { uint32_t p = atomicAdd(&s_bcnt, 1u); if (p < BUCKET_CAP) bkt[p] = make_uint2(c0.x, c0.y); }
    if (bin_of(c0.z) == bsel) { uint32_t p = atomicAdd(&s_bcnt, 1u); if (p < BUCKET_CAP) bkt[p] = make_uint2(c0.z, c0.w); }
    if (bin_of(c1.x) == bsel) { uint32_t p = atomicAdd(&s_bcnt, 1u); if (p < BUCKET_CAP) bkt[p] = make_uint2(c1.x, c1.y); }
    if (bin_of(c1.z) == bsel) { uint32_t p = atomicAdd(&s_bcnt, 1u); if (p < BUCKET_CAP) bkt[p] = make_uint2(c1.z, c1.w); }
    if (bin_of(c2.x) == bsel) { uint32_t p = atomicAdd(&s_bcnt, 1u); if (p < BUCKET_CAP) bkt[p] = make_uint2(c2.x, c2.y); }
    if (bin_of(c2.z) == bsel) { uint32_t p = atomicAdd(&s_bcnt, 1u); if (p < BUCKET_CAP) bkt[p] = make_uint2(c2.z, c2.w); }
    if (bin_of(c3.x) == bsel) { uint32_t p = atomicAdd(&s_bcnt, 1u); if (p < BUCKET_CAP) bkt[p] = make_uint2(c3.x, c3.y); }
    if (bin_of(c3.z) == bsel) { uint32_t p = atomicAdd(&s_bcnt, 1u); if (p < BUCKET_CAP) bkt[p] = make_uint2(c3.z, c3.w); }
  }
  for (; j < M2; j += 1024u) {
    uint4 c = cand4[j];
    if (bin_of(c.x) == bsel) { uint32_t p = atomicAdd(&s_bcnt, 1u); if (p < BUCKET_CAP) bkt[p] = make_uint2(c.x, c.y); }
    if (bin_of(c.z) == bsel) { uint32_t p = atomicAdd(&s_bcnt, 1u); if (p < BUCKET_CAP) bkt[p] = make_uint2(c.z, c.w); }
  }
  if (tid == 0u && (M & 1u)) {
    uint2 c = cand[M - 1u];
    if (bin_of(c.x) == bsel) { uint32_t p = atomicAdd(&s_bcnt, 1u); if (p < BUCKET_CAP) bkt[p] = c; }
  }
  __syncthreads();
  // exact selection: entry with composite rank r-1 (key desc, idx asc)
  for (uint32_t e = tid; e < E; e += 1024u) {
    uint2 me = bkt[e];
    uint32_t rank = 0u;
    for (uint32_t jj = 0; jj < E; ++jj) {
      uint2 o = bkt[jj];
      rank += (o.x > me.x || (o.x == me.x && o.y < me.y)) ? 1u : 0u;
    }
    if (rank == r - 1u) { hdr[HDR_THR] = me.x; hdr[HDR_ICUT] = me.y; }
  }
}

// Sparse scatter of kept candidates into the zeroed output.
__global__ __launch_bounds__(256) void k_scatter(
    const uint2* __restrict__ cand, const uint32_t* __restrict__ hdr,
    float* __restrict__ out, uint32_t cap) {
  if (hdr[HDR_FLAG] != 0u) return;
  uint32_t M = hdr[HDR_CURSOR]; if (M > cap) M = cap;
  uint32_t thr = hdr[HDR_THR], icut = hdr[HDR_ICUT];
  uint32_t stride = gridDim.x * blockDim.x;
  for (uint32_t i = blockIdx.x * blockDim.x + threadIdx.x; i < M; i += stride) {
    uint2 c = cand[i];
    if (c.x > thr || (c.x == thr && c.y <= icut)) out[c.y] = __uint_as_float(c.x);
  }
}

// Exact general fallback (gated; never taken for the fixed bench input).
// Single block, full radix select over all data + dense rewrite. Slow but correct.
__global__ __launch_bounds__(1024) void k_fallback(
    const float* __restrict__ x, float* __restrict__ out,
    const int* __restrict__ kptr, const uint32_t* __restrict__ hdr, uint32_t n) {
  if (hdr[HDR_FLAG] == 0u) return;
  __shared__ uint32_t hist[2048];
  __shared__ uint32_t s_sel, s_rank, s_found, s_eqcnt, s_icut;
  __shared__ uint32_t eq_idx[4096];
  uint32_t tid = threadIdx.x;
  uint32_t K = (uint32_t)kptr[0] * ROWS;
  uint32_t prefix = 0u;
  uint32_t R = K;
  bool zero_thr = (K == 0u);
  for (int lvl = 0; lvl < 3 && !zero_thr; ++lvl) {
    uint32_t shift = (lvl == 0) ? 21u : (lvl == 1 ? 10u : 0u);
    uint32_t nb = (lvl == 2) ? 1024u : 2048u;
    for (uint32_t b = tid; b < nb; b += 1024u) hist[b] = 0u;
    __syncthreads();
    for (uint32_t i = tid; i < n; i += 1024u) {
      float v = x[i];
      uint32_t key = (v > 0.f) ? __float_as_uint(v) : 0u;
      bool valid = (key != 0u);
      if (lvl == 1) valid = valid && ((key >> 21) == prefix);
      if (lvl == 2) valid = valid && ((key >> 10) == prefix);
      if (valid) atomicAdd(&hist[(key >> shift) & (nb - 1u)], 1u);
    }
    __syncthreads();
    if (tid == 0u) {
      uint32_t cum = 0u, sel = 0u, rr = R, found = 0u;
      for (int b = (int)nb - 1; b >= 0; --b) {
        uint32_t c = hist[b];
        if (cum + c >= R) { sel = (uint32_t)b; rr = R - cum; found = 1u; break; }
        cum += c;
      }
      s_sel = sel; s_rank = rr; s_found = found;
    }
    __syncthreads();
    if (s_found == 0u) {
      zero_thr = true;  // fewer than K positives: keep all positives
    } else {
      uint32_t sel = s_sel;
      R = s_rank;
      if (lvl == 0) prefix = sel;
      else if (lvl == 1) prefix = (prefix << 11) | sel;
      else prefix = (prefix << 10) | sel;
    }
    __syncthreads();
  }
  uint32_t thr_key = zero_thr ? 0u : prefix;
  uint32_t icut = 0xFFFFFFFFu;
  if (!zero_thr) {
    uint32_t E = hist[thr_key & 1023u];
    uint32_t T = R;
    if (T < E) {
      if (tid == 0u) { s_eqcnt = 0u; s_icut = 0xFFFFFFFFu; }
      __syncthreads();
      for (uint32_t i = tid; i < n; i += 1024u) {
        float v = x[i];
        if (v > 0.f && __float_as_uint(v) == thr_key) {
          uint32_t p = atomicAdd(&s_eqcnt, 1u);
          if (p < 4096u) eq_idx[p] = i;
        }
      }
      __syncthreads();
      uint32_t ec = s_eqcnt < 4096u ? s_eqcnt : 4096u;
      for (uint32_t e = tid; e < ec; e += 1024u) {
        uint32_t me = eq_idx[e];
        uint32_t rank = 0u;
        for (uint32_t j = 0; j < ec; ++j) rank += (eq_idx[j] < me) ? 1u : 0u;
        if (rank == T - 1u) s_icut = me;
      }
      __syncthreads();
      icut = s_icut;
    }
  }
  for (uint32_t i = tid; i < n; i += 1024u) {
    float v = x[i];
    uint32_t key = (v > 0.f) ? __float_as_uint(v) : 0u;
    bool keep = (key > thr_key) || (key != 0u && key == thr_key && i <= icut);
    out[i] = keep ? v : 0.f;
  }
}

extern "C" void kernel_launch(void* const* d_in, const int* in_sizes, int n_in,
                              void* d_out, int out_size, void* d_ws, size_t ws_size,
                              hipStream_t stream) {
  const float* x = (const float*)d_in[0];
  const int* kptr = (const int*)d_in[1];
  float* out = (float*)d_out;
  uint32_t n = (uint32_t)in_sizes[0];
  uint32_t n4 = n >> 2;

  uint32_t* hdr = (uint32_t*)d_ws;
  uint32_t* ghist = (uint32_t*)((char*)d_ws + HIST_OFF);
  uint2* cand = (uint2*)((char*)d_ws + CAND_OFF);
  uint32_t cap = (ws_size > (size_t)CAND_OFF) ? (uint32_t)((ws_size - CAND_OFF) / 8) : 0u;
  // If ws can't hold candidates with margin, force the exact fallback path.
  uint32_t force = (cap < 131072u) ? 1u : 0u;

  k_init<<<1, 256, 0, stream>>>(hdr, ghist, force);
  k_scan<<<2048, 256, 0, stream>>>((const float4*)x, x, cand, hdr, ghist, cap, n4, n);
  // Zero the output via the rocclr fill path (plain stores, 6.6 TB/s measured).
  hipMemsetAsync(out, 0, (size_t)n * 4u, stream);
  k_select<<<1, 1024, 0, stream>>>(cand, hdr, ghist, kptr, cap);
  k_fallback<<<1, 1024, 0, stream>>>(x, out, kptr, hdr, n);
  k_scatter<<<512, 256, 0, stream>>>(cand, hdr, out, cap);
}

// Round 6
// 484.808 us; speedup vs baseline: 2.0076x; 1.0354x over previous
//
#include <hip/hip_runtime.h>
#include <stdint.h>

// BatchTopK: x (1024, 65536) f32, keep global top k*1024 = 65536 of relu(x), zero rest.
//
// R11: shave the controllable tail; confirm the structural floor.
// Surviving model (R6-R10): dur = ~330-370us harness poison fills @6.5TB/s
// (HW peak, outside kernel_launch) + ~130-170us ours. Two scan restructures
// (R9 strided-deep, R10 contiguous) were NEUTRAL -> scan is ~60us L3-assisted
// and near its limit. Remaining slack: launch count + select's 1-CU collect.
// Changes:
//  (a) k_init kernel -> hipMemsetAsync(ws, 0, 12KB) memset node.
//  (b) k_select + k_fallback merged into k_finish (fallback inlined in the
//      same 1024-thread block, LDS unioned at 56KB); one fewer launch.
//  (c) scan: wave-contiguous 4-deep (4KB contiguous per wave, 4 loads in
//      flight, ballot per float4 -> ~71% skip).

#define HDR_CURSOR 0
#define HDR_FLAG   1
#define HDR_THR    2
#define HDR_ICUT   3
#define HIST_OFF   4096       // uint32 ghist[2048] at ws+4096
#define CAND_OFF   16384      // candidate buffer
#define NBINS      2048u
#define BUCKET_CAP 6144u
#define SCAN_STAGE 1024       // per-block candidate staging (expected ~44/block)
#define ROWS       1024u      // x.shape[0], fixed by the problem
#define SPEC       3.0f       // count(x>=3.0) ~ 90.6k >= K=65536
#define BASE_BITS  0x40400000u  // __float_as_uint(3.0f)

__device__ __forceinline__ uint32_t bin_of(uint32_t key) {
  uint32_t off = key - BASE_BITS;        // key >= BASE_BITS guaranteed by SPEC filter
  uint32_t b = off >> 12;
  return b < NBINS ? b : (NBINS - 1u);
}

__device__ __forceinline__ float max4(float4 a) {
  return fmaxf(fmaxf(a.x, a.y), fmaxf(a.z, a.w));
}

// Only used on the forced-fallback path (tiny workspace).
__global__ void k_init(uint32_t* hdr, uint32_t* ghist, uint32_t force_flag) {
  for (uint32_t i = threadIdx.x; i < 64u + NBINS; i += 256u) {
    if (i < 64u) hdr[i] = 0u;
    else ghist[i - 64u] = 0u;
  }
  if (threadIdx.x == 0u) hdr[HDR_FLAG] = force_flag;
}

__device__ __forceinline__ void push4(float4 a, uint32_t gi,
                                      uint32_t* s_cnt, uint2* s_buf) {
  if (a.x >= SPEC) { uint32_t p = atomicAdd(s_cnt, 1u); if (p < SCAN_STAGE) s_buf[p] = make_uint2(__float_as_uint(a.x), gi); }
  if (a.y >= SPEC) { uint32_t p = atomicAdd(s_cnt, 1u); if (p < SCAN_STAGE) s_buf[p] = make_uint2(__float_as_uint(a.y), gi + 1u); }
  if (a.z >= SPEC) { uint32_t p = atomicAdd(s_cnt, 1u); if (p < SCAN_STAGE) s_buf[p] = make_uint2(__float_as_uint(a.z), gi + 2u); }
  if (a.w >= SPEC) { uint32_t p = atomicAdd(s_cnt, 1u); if (p < SCAN_STAGE) s_buf[p] = make_uint2(__float_as_uint(a.w), gi + 3u); }
}

// Read-only scan: each wave reads a 4KB-contiguous chunk (4 x 1KB dense loads
// in flight), ballot per float4 (~71% skip). Grid-strided over 256-float4 chunks.
__global__ __launch_bounds__(256) void k_scan(
    const float4* __restrict__ x4, const float* __restrict__ x,
    uint2* __restrict__ cand, uint32_t* __restrict__ hdr,
    uint32_t* __restrict__ ghist,
    uint32_t cap, uint32_t n4, uint32_t n) {
  __shared__ uint32_t s_cnt;
  __shared__ uint32_t s_base;
  __shared__ uint2 s_buf[SCAN_STAGE];
  uint32_t tid = threadIdx.x;
  if (tid == 0u) s_cnt = 0u;
  __syncthreads();

  uint32_t lane = tid & 63u;
  uint32_t gwid = (blockIdx.x * blockDim.x + tid) >> 6;   // global wave id
  uint32_t nw   = (gridDim.x * blockDim.x) >> 6;          // total waves
  uint32_t nchunk = n4 >> 8;                              // 256-float4 chunks
  for (uint32_t c = gwid; c < nchunk; c += nw) {
    uint32_t base = c << 8;
    float4 a0 = x4[base + lane];
    float4 a1 = x4[base + 64u + lane];
    float4 a2 = x4[base + 128u + lane];
    float4 a3 = x4[base + 192u + lane];
    if (__ballot(max4(a0) >= SPEC)) push4(a0, (base + lane) * 4u, &s_cnt, s_buf);
    if (__ballot(max4(a1) >= SPEC)) push4(a1, (base + 64u + lane) * 4u, &s_cnt, s_buf);
    if (__ballot(max4(a2) >= SPEC)) push4(a2, (base + 128u + lane) * 4u, &s_cnt, s_buf);
    if (__ballot(max4(a3) >= SPEC)) push4(a3, (base + 192u + lane) * 4u, &s_cnt, s_buf);
  }
  // remainder float4s (none for the bench shape) + scalar tail
  uint32_t rem0 = nchunk << 8;
  if (blockIdx.x == 0u) {
    for (uint32_t i = rem0 + tid; i < n4; i += blockDim.x) {
      float4 a = x4[i];
      if (__ballot(max4(a) >= SPEC)) push4(a, i * 4u, &s_cnt, s_buf);
    }
    uint32_t tail0 = n4 * 4u;
    if (tid < (n - tail0)) {
      uint32_t gi = tail0 + tid;
      float v = x[gi];
      if (v >= SPEC) { uint32_t p = atomicAdd(&s_cnt, 1u); if (p < SCAN_STAGE) s_buf[p] = make_uint2(__float_as_uint(v), gi); }
    }
  }
  __syncthreads();
  uint32_t cnt = s_cnt;
  if (cnt == 0u) return;
  uint32_t wcnt = cnt < (uint32_t)SCAN_STAGE ? cnt : (uint32_t)SCAN_STAGE;
  if (tid == 0u) {
    s_base = atomicAdd(&hdr[HDR_CURSOR], cnt);  // true total (drops flagged)
    if (cnt > (uint32_t)SCAN_STAGE) atomicOr(&hdr[HDR_FLAG], 1u);
  }
  __syncthreads();
  uint32_t base = s_base;
  for (uint32_t j = tid; j < wcnt; j += blockDim.x) {
    uint32_t gidx = base + j;
    if (gidx < cap) {
      uint2 c = s_buf[j];
      cand[gidx] = c;
      atomicAdd(&ghist[bin_of(c.x)], 1u);   // ~44/block, spread over 2048 words
    }
  }
  if (tid == 0u && base + wcnt > cap) atomicOr(&hdr[HDR_FLAG], 1u);
}

// Single block: select (2048-bin suffix scan + bucket collect + exact rank);
// on any abort, the exact full-radix fallback runs inline in the same block.
__global__ __launch_bounds__(1024) void k_finish(
    const uint2* __restrict__ cand, uint32_t* __restrict__ hdr,
    const uint32_t* __restrict__ ghist, const int* __restrict__ kptr,
    const float* __restrict__ x, float* __restrict__ out,
    uint32_t cap, uint32_t n) {
  __shared__ __align__(16) uint8_t smem[57344];          // 56 KB union
  uint32_t* h      = (uint32_t*)smem;                    // select hist / fb hist
  uint2*    bkt    = (uint2*)(smem + 8192);              // select bucket (48KB)
  uint32_t* eq_idx = (uint32_t*)(smem + 8192);           // fb eq-scan (16KB, aliases bkt)
  __shared__ uint32_t s_sel, s_rank, s_bcnt, s_need, s_found, s_eqcnt, s_icut;
  uint32_t tid = threadIdx.x;
  uint32_t K = (uint32_t)kptr[0] * ROWS;
  uint32_t M = hdr[HDR_CURSOR];
  if (tid == 0u) s_need = 0u;
  __syncthreads();

  // ---------------- select phase (block-uniform branching) ----------------
  bool skip_sel = (hdr[HDR_FLAG] != 0u || M > cap || M < K);
  if (skip_sel) {
    if (tid == 0u) s_need = 1u;
  } else if (K == 0u) {
    // keep nothing; candidate keys are finite positive floats < 0xFFFFFFFF
    if (tid == 0u) { hdr[HDR_THR] = 0xFFFFFFFFu; hdr[HDR_ICUT] = 0xFFFFFFFFu; }
    return;
  } else {
    h[tid] = ghist[tid];
    h[tid + 1024u] = ghist[tid + 1024u];
    if (tid == 0u) s_bcnt = 0u;
    __syncthreads();
    // wave 0: suffix scan over 2048 bins to find the bin holding rank K
    if (tid < 64u) {
      uint32_t seg = NBINS >> 6;           // 32 bins per lane
      uint32_t base = tid * seg;
      uint32_t lanesum = 0u;
      for (uint32_t j = 0; j < seg; ++j) lanesum += h[base + j];
      uint32_t s = lanesum;                // inclusive suffix scan across lanes
      for (int d = 1; d < 64; d <<= 1) {
        uint32_t v = (uint32_t)__shfl_down((int)s, d, 64);
        if ((int)tid + d < 64) s += v;
      }
      uint32_t above = s - lanesum;        // total count in lanes > tid
      if (above < K && above + lanesum >= K) {   // exactly one lane matches
        uint32_t r = K - above;
        uint32_t cum = 0u;
        for (int j = (int)seg - 1; j >= 0; --j) {
          uint32_t c = h[base + (uint32_t)j];
          if (cum + c >= r) { s_sel = base + (uint32_t)j; s_rank = r - cum; break; }
          cum += c;
        }
      }
    }
    __syncthreads();
    uint32_t bsel = s_sel;
    uint32_t r = s_rank;                   // 1-indexed rank inside the bin
    uint32_t E = h[bsel];
    if (bsel == NBINS - 1u || E > BUCKET_CAP) {  // clamp bin or oversized bucket
      if (tid == 0u) s_need = 1u;
    } else {
      // collect candidates in bin bsel (x4 unrolled, 8 keys/iter)
      const uint4* __restrict__ cand4 = (const uint4*)cand;
      uint32_t M2 = M >> 1;
      uint32_t j = tid;
      for (; j + 3072u < M2; j += 4096u) {
        uint4 c0 = cand4[j];
        uint4 c1 = cand4[j + 1024u];
        uint4 c2 = cand4[j + 2048u];
        uint4 c3 = cand4[j + 3072u];
        if (bin_of(c0.x) == bsel) { uint32_t p = atomicAdd(&s_bcnt, 1u); if (p < BUCKET_CAP) bkt[p] = make_uint2(c0.x, c0.y); }
        if (bin_of(c0.z) == bsel) { uint32_t p = atomicAdd(&s_bcnt, 1u); if (p < BUCKET_CAP) bkt[p] = make_uint2(c0.z, c0.w); }
        if (bin_of(c1.x) == bsel) { uint32_t p = atomicAdd(&s_bcnt, 1u); if (p < BUCKET_CAP) bkt[p] = make_uint2(c1.x, c1.y); }
        if (bin_of(c1.z) == bsel) { uint32_t p = atomicAdd(&s_bcnt, 1u); if (p < BUCKET_CAP) bkt[p] = make_uint2(c1.z, c1.w); }
        if (bin_of(c2.x) == bsel) { uint32_t p = atomicAdd(&s_bcnt, 1u); if (p < BUCKET_CAP) bkt[p] = make_uint2(c2.x, c2.y); }
        if (bin_of(c2.z) == bsel) { uint32_t p = atomicAdd(&s_bcnt, 1u); if (p < BUCKET_CAP) bkt[p] = make_uint2(c2.z, c2.w); }
        if (bin_of(c3.x) == bsel) { uint32_t p = atomicAdd(&s_bcnt, 1u); if (p < BUCKET_CAP) bkt[p] = make_uint2(c3.x, c3.y); }
        if (bin_of(c3.z) == bsel) { uint32_t p = atomicAdd(&s_bcnt, 1u); if (p < BUCKET_CAP) bkt[p] = make_uint2(c3.z, c3.w); }
      }
      for (; j < M2; j += 1024u) {
        uint4 c = cand4[j];
        if (bin_of(c.x) == bsel) { uint32_t p = atomicAdd(&s_bcnt, 1u); if (p < BUCKET_CAP) bkt[p] = make_uint2(c.x, c.y); }
        if (bin_of(c.z) == bsel) { uint32_t p = atomicAdd(&s_bcnt, 1u); if (p < BUCKET_CAP) bkt[p] = make_uint2(c.z, c.w); }
      }
      if (tid == 0u && (M & 1u)) {
        uint2 c = cand[M - 1u];
        if (bin_of(c.x) == bsel) { uint32_t p = atomicAdd(&s_bcnt, 1u); if (p < BUCKET_CAP) bkt[p] = c; }
      }
      __syncthreads();
      // exact selection: entry with composite rank r-1 (key desc, idx asc)
      for (uint32_t e = tid; e < E; e += 1024u) {
        uint2 me = bkt[e];
        uint32_t rank = 0u;
        for (uint32_t jj = 0; jj < E; ++jj) {
          uint2 o = bkt[jj];
          rank += (o.x > me.x || (o.x == me.x && o.y < me.y)) ? 1u : 0u;
        }
        if (rank == r - 1u) { hdr[HDR_THR] = me.x; hdr[HDR_ICUT] = me.y; }
      }
    }
  }
  __syncthreads();
  if (s_need == 0u) return;
  if (tid == 0u) hdr[HDR_FLAG] = 1u;   // k_scatter will skip

  // ---------------- exact fallback (inline, same block) ----------------
  uint32_t prefix = 0u;
  uint32_t R = K;
  bool zero_thr = (K == 0u);
  for (int lvl = 0; lvl < 3 && !zero_thr; ++lvl) {
    uint32_t shift = (lvl == 0) ? 21u : (lvl == 1 ? 10u : 0u);
    uint32_t nb = (lvl == 2) ? 1024u : 2048u;
    for (uint32_t b = tid; b < nb; b += 1024u) h[b] = 0u;
    __syncthreads();
    for (uint32_t i = tid; i < n; i += 1024u) {
      float v = x[i];
      uint32_t key = (v > 0.f) ? __float_as_uint(v) : 0u;
      bool valid = (key != 0u);
      if (lvl == 1) valid = valid && ((key >> 21) == prefix);
      if (lvl == 2) valid = valid && ((key >> 10) == prefix);
      if (valid) atomicAdd(&h[(key >> shift) & (nb - 1u)], 1u);
    }
    __syncthreads();
    if (tid == 0u) {
      uint32_t cum = 0u, sel = 0u, rr = R, found = 0u;
      for (int b = (int)nb - 1; b >= 0; --b) {
        uint32_t c = h[b];
        if (cum + c >= R) { sel = (uint32_t)b; rr = R - cum; found = 1u; break; }
        cum += c;
      }
      s_sel = sel; s_rank = rr; s_found = found;
    }
    __syncthreads();
    if (s_found == 0u) {
      zero_thr = true;  // fewer than K positives: keep all positives
    } else {
      uint32_t sel = s_sel;
      R = s_rank;
      if (lvl == 0) prefix = sel;
      else if (lvl == 1) prefix = (prefix << 11) | sel;
      else prefix = (prefix << 10) | sel;
    }
    __syncthreads();
  }
  uint32_t thr_key = zero_thr ? 0u : prefix;
  uint32_t icut = 0xFFFFFFFFu;
  if (!zero_thr) {
    uint32_t E2 = h[thr_key & 1023u];
    uint32_t T = R;
    if (T < E2) {
      if (tid == 0u) { s_eqcnt = 0u; s_icut = 0xFFFFFFFFu; }
      __syncthreads();
      for (uint32_t i = tid; i < n; i += 1024u) {
        float v = x[i];
        if (v > 0.f && __float_as_uint(v) == thr_key) {
          uint32_t p = atomicAdd(&s_eqcnt, 1u);
          if (p < 4096u) eq_idx[p] = i;
        }
      }
      __syncthreads();
      uint32_t ec = s_eqcnt < 4096u ? s_eqcnt : 4096u;
      for (uint32_t e = tid; e < ec; e += 1024u) {
        uint32_t me = eq_idx[e];
        uint32_t rank = 0u;
        for (uint32_t j = 0; j < ec; ++j) rank += (eq_idx[j] < me) ? 1u : 0u;
        if (rank == T - 1u) s_icut = me;
      }
      __syncthreads();
      icut = s_icut;
    }
  }
  for (uint32_t i = tid; i < n; i += 1024u) {
    float v = x[i];
    uint32_t key = (v > 0.f) ? __float_as_uint(v) : 0u;
    bool keep = (key > thr_key) || (key != 0u && key == thr_key && i <= icut);
    out[i] = keep ? v : 0.f;
  }
}

// Sparse scatter of kept candidates into the zeroed output.
__global__ __launch_bounds__(256) void k_scatter(
    const uint2* __restrict__ cand, const uint32_t* __restrict__ hdr,
    float* __restrict__ out, uint32_t cap) {
  if (hdr[HDR_FLAG] != 0u) return;
  uint32_t M = hdr[HDR_CURSOR]; if (M > cap) M = cap;
  uint32_t thr = hdr[HDR_THR], icut = hdr[HDR_ICUT];
  uint32_t stride = gridDim.x * blockDim.x;
  for (uint32_t i = blockIdx.x * blockDim.x + threadIdx.x; i < M; i += stride) {
    uint2 c = cand[i];
    if (c.x > thr || (c.x == thr && c.y <= icut)) out[c.y] = __uint_as_float(c.x);
  }
}

extern "C" void kernel_launch(void* const* d_in, const int* in_sizes, int n_in,
                              void* d_out, int out_size, void* d_ws, size_t ws_size,
                              hipStream_t stream) {
  const float* x = (const float*)d_in[0];
  const int* kptr = (const int*)d_in[1];
  float* out = (float*)d_out;
  uint32_t n = (uint32_t)in_sizes[0];
  uint32_t n4 = n >> 2;

  uint32_t* hdr = (uint32_t*)d_ws;
  uint32_t* ghist = (uint32_t*)((char*)d_ws + HIST_OFF);
  uint2* cand = (uint2*)((char*)d_ws + CAND_OFF);
  uint32_t cap = (ws_size > (size_t)CAND_OFF) ? (uint32_t)((ws_size - CAND_OFF) / 8) : 0u;

  if (cap < 131072u) {
    // ws too small for candidates: zero headers AND force the exact fallback.
    k_init<<<1, 256, 0, stream>>>(hdr, ghist, 1u);
  } else {
    // zero hdr (256B used) + ghist (8KB @ +4096) in one memset node
    hipMemsetAsync(d_ws, 0, 12288, stream);
  }
  k_scan<<<2048, 256, 0, stream>>>((const float4*)x, x, cand, hdr, ghist, cap, n4, n);
  // Zero the output via the rocclr fill path (plain stores, 6.5 TB/s measured).
  hipMemsetAsync(out, 0, (size_t)n * 4u, stream);
  k_finish<<<1, 1024, 0, stream>>>(cand, hdr, ghist, kptr, x, out, cap, n);
  k_scatter<<<512, 256, 0, stream>>>(cand, hdr, out, cap);
}